// Round 1
// baseline (1760.146 us; speedup 1.0000x reference)
//
#include <hip/hip_runtime.h>
#include <math.h>

#define N_NODES 50000
#define N_EDGES 800000
#define DIM 128
#define EDIM 64
#define NH 4

// float atomic max via signed-max (v>=0) / unsigned-min (v<0); init must be -inf
__device__ __forceinline__ void atomicMaxF(float* addr, float v) {
    if (v >= 0.0f) atomicMax((int*)addr, __float_as_int(v));
    else           atomicMin((unsigned int*)addr, __float_as_uint(v));
}

__global__ __launch_bounds__(256) void k_init(float* maxv, float* sumv, float* context) {
    size_t i = (size_t)blockIdx.x * blockDim.x + threadIdx.x;
    size_t stride = (size_t)gridDim.x * blockDim.x;
    if (i < (size_t)N_NODES * NH) { maxv[i] = -INFINITY; sumv[i] = 0.0f; }
    for (size_t j = i; j < (size_t)N_NODES * DIM; j += stride) context[j] = 0.0f;
}

// 32 nodes/block, 128 threads. Computes Vx = x@value_w + value_b, and the
// per-node halves of the alignment score: a_dst = x@aw[0:128], a_src = x@aw[128:256].
__global__ __launch_bounds__(128) void k_node_pre(
    const float* __restrict__ x, const float* __restrict__ vw, const float* __restrict__ vb,
    const float* __restrict__ aw, float* __restrict__ Vx,
    float* __restrict__ a_dst, float* __restrict__ a_src) {
    __shared__ float xs[32][129];   // +1 pad: conflict-free row-strided reads
    int t = threadIdx.x;
    int nb = blockIdx.x * 32;
    #pragma unroll
    for (int i = 0; i < 8; ++i) {
        int idx = i * 128 + t;
        int m = idx >> 5, k4 = idx & 31;
        int n = nb + m;
        float4 v = make_float4(0.f, 0.f, 0.f, 0.f);
        if (n < N_NODES) v = *(const float4*)(x + (size_t)n * DIM + k4 * 4);
        xs[m][k4*4+0] = v.x; xs[m][k4*4+1] = v.y; xs[m][k4*4+2] = v.z; xs[m][k4*4+3] = v.w;
    }
    __syncthreads();
    int c = t & 31, mg = t >> 5;          // 32 col-groups x 4 node-groups
    int d0 = c * 4, m0 = mg * 8;          // 4 cols, 8 nodes per thread
    float acc[8][4];
    #pragma unroll
    for (int j = 0; j < 8; ++j) { acc[j][0]=0.f; acc[j][1]=0.f; acc[j][2]=0.f; acc[j][3]=0.f; }
    for (int k = 0; k < DIM; ++k) {
        float4 w = *(const float4*)(vw + (size_t)k * DIM + d0);   // coalesced, L1/L2-hot
        #pragma unroll
        for (int j = 0; j < 8; ++j) {
            float xv = xs[m0 + j][k];                              // broadcast within half-wave
            acc[j][0] += xv * w.x; acc[j][1] += xv * w.y;
            acc[j][2] += xv * w.z; acc[j][3] += xv * w.w;
        }
    }
    float4 vb4 = *(const float4*)(vb + d0);
    #pragma unroll
    for (int j = 0; j < 8; ++j) {
        int n = nb + m0 + j;
        if (n < N_NODES) {
            float4 o = make_float4(acc[j][0]+vb4.x, acc[j][1]+vb4.y,
                                   acc[j][2]+vb4.z, acc[j][3]+vb4.w);
            *(float4*)(Vx + (size_t)n * DIM + d0) = o;
        }
    }
    // a_dst / a_src: 32 nodes * 8 outputs = 256 dots of length 128; 2 per thread
    #pragma unroll
    for (int oo = 0; oo < 2; ++oo) {
        int o = t * 2 + oo;
        int m = o >> 3, jj = o & 7, p = jj >> 2, h = jj & 3;
        float s = 0.f;
        for (int k = 0; k < DIM; ++k) s += xs[m][k] * aw[(size_t)(p * DIM + k) * NH + h];
        int n = nb + m;
        if (n < N_NODES) { (p ? a_src : a_dst)[(size_t)n * NH + h] = s; }
    }
}

// 16 lanes per edge: coalesced 256B edge_attr read, shuffle-reduced 64-wide dot
// per head, + per-node terms; stores scores[E,4] and atomic-max into maxv[N,4].
__global__ __launch_bounds__(256) void k_edge_scores(
    const float* __restrict__ ea, const int* __restrict__ ei,
    const float* __restrict__ aw, const float* __restrict__ ab,
    const float* __restrict__ a_dst, const float* __restrict__ a_src,
    float* __restrict__ scores, float* __restrict__ maxv) {
    __shared__ float s_awe[256];   // aw rows 256..319, [k][h]
    __shared__ float s_b[4];
    int t = threadIdx.x;
    s_awe[t] = aw[1024 + t];
    if (t < 4) s_b[t] = ab[t];
    __syncthreads();
    int l = t & 15, g = t >> 4;
    for (int e = blockIdx.x * 16 + g; e < N_EDGES; e += gridDim.x * 16) {
        float4 v = *(const float4*)(ea + (size_t)e * EDIM + l * 4);
        float vv[4] = {v.x, v.y, v.z, v.w};
        float p[4] = {0.f, 0.f, 0.f, 0.f};
        #pragma unroll
        for (int j = 0; j < 4; ++j)
            #pragma unroll
            for (int h = 0; h < NH; ++h)
                p[h] += vv[j] * s_awe[(l*4+j)*4 + h];
        #pragma unroll
        for (int off = 1; off < 16; off <<= 1) {
            #pragma unroll
            for (int h = 0; h < NH; ++h) p[h] += __shfl_xor(p[h], off);
        }
        if (l == 0) {
            int row = ei[e], col = ei[N_EDGES + e];
            float4 ad  = *(const float4*)(a_dst + (size_t)row * NH);
            float4 as_ = *(const float4*)(a_src + (size_t)col * NH);
            float s0 = p[0] + ad.x + as_.x + s_b[0];
            float s1 = p[1] + ad.y + as_.y + s_b[1];
            float s2 = p[2] + ad.z + as_.z + s_b[2];
            float s3 = p[3] + ad.w + as_.w + s_b[3];
            *(float4*)(scores + (size_t)e * 4) = make_float4(s0, s1, s2, s3);
            float* mp = maxv + (size_t)row * NH;
            atomicMaxF(mp+0, s0); atomicMaxF(mp+1, s1);
            atomicMaxF(mp+2, s2); atomicMaxF(mp+3, s3);
        }
    }
}

__global__ __launch_bounds__(256) void k_exp_sum(
    const int* __restrict__ ei, float* __restrict__ scores,
    const float* __restrict__ maxv, float* __restrict__ sumv) {
    for (int e = blockIdx.x * blockDim.x + threadIdx.x; e < N_EDGES;
         e += gridDim.x * blockDim.x) {
        int row = ei[e];
        float4 s = *(float4*)(scores + (size_t)e * 4);
        float4 m = *(const float4*)(maxv + (size_t)row * NH);
        float4 r;
        r.x = __expf(s.x - m.x); r.y = __expf(s.y - m.y);
        r.z = __expf(s.z - m.z); r.w = __expf(s.w - m.w);
        *(float4*)(scores + (size_t)e * 4) = r;
        float* sp = sumv + (size_t)row * NH;
        atomicAdd(sp+0, r.x); atomicAdd(sp+1, r.y);
        atomicAdd(sp+2, r.z); atomicAdd(sp+3, r.w);
    }
}

// 32 lanes per edge: context[row, :] += Vx[col, :] * alpha[head]
__global__ __launch_bounds__(256) void k_scatter(
    const int* __restrict__ ei, const float* __restrict__ scores,
    const float* __restrict__ sumv, const float* __restrict__ Vx,
    float* __restrict__ context) {
    int t = threadIdx.x;
    int l = t & 31, g = t >> 5;
    for (int e = blockIdx.x * 8 + g; e < N_EDGES; e += gridDim.x * 8) {
        int row = ei[e], col = ei[N_EDGES + e];
        int h = l >> 3;                       // lane's 4 dims all in head h
        float al = scores[(size_t)e * 4 + h] / (sumv[(size_t)row * NH + h] + 1e-8f);
        float4 v = *(const float4*)(Vx + (size_t)col * DIM + l * 4);
        float* cp = context + (size_t)row * DIM + l * 4;
        atomicAdd(cp+0, v.x*al); atomicAdd(cp+1, v.y*al);
        atomicAdd(cp+2, v.z*al); atomicAdd(cp+3, v.w*al);
    }
}

// y = x + context@proj_w + proj_b; layernorm over D, in-register shuffle reduce.
__global__ __launch_bounds__(128) void k_final(
    const float* __restrict__ x, const float* __restrict__ context,
    const float* __restrict__ pw, const float* __restrict__ pb,
    const float* __restrict__ lg, const float* __restrict__ lb,
    float* __restrict__ out) {
    __shared__ float cs[32][129];
    int t = threadIdx.x;
    int nb = blockIdx.x * 32;
    #pragma unroll
    for (int i = 0; i < 8; ++i) {
        int idx = i * 128 + t;
        int m = idx >> 5, k4 = idx & 31;
        int n = nb + m;
        float4 v = make_float4(0.f, 0.f, 0.f, 0.f);
        if (n < N_NODES) v = *(const float4*)(context + (size_t)n * DIM + k4 * 4);
        cs[m][k4*4+0] = v.x; cs[m][k4*4+1] = v.y; cs[m][k4*4+2] = v.z; cs[m][k4*4+3] = v.w;
    }
    __syncthreads();
    int c = t & 31, mg = t >> 5;
    int d0 = c * 4, m0 = mg * 8;
    float acc[8][4];
    #pragma unroll
    for (int j = 0; j < 8; ++j) { acc[j][0]=0.f; acc[j][1]=0.f; acc[j][2]=0.f; acc[j][3]=0.f; }
    for (int k = 0; k < DIM; ++k) {
        float4 w = *(const float4*)(pw + (size_t)k * DIM + d0);
        #pragma unroll
        for (int j = 0; j < 8; ++j) {
            float cv = cs[m0 + j][k];
            acc[j][0] += cv * w.x; acc[j][1] += cv * w.y;
            acc[j][2] += cv * w.z; acc[j][3] += cv * w.w;
        }
    }
    float4 pb4 = *(const float4*)(pb + d0);
    float4 g4  = *(const float4*)(lg + d0);
    float4 b4  = *(const float4*)(lb + d0);
    #pragma unroll
    for (int j = 0; j < 8; ++j) {
        int n = nb + m0 + j;
        float4 xv = make_float4(0.f, 0.f, 0.f, 0.f);
        if (n < N_NODES) xv = *(const float4*)(x + (size_t)n * DIM + d0);
        float y0 = xv.x + acc[j][0] + pb4.x;
        float y1 = xv.y + acc[j][1] + pb4.y;
        float y2 = xv.z + acc[j][2] + pb4.z;
        float y3 = xv.w + acc[j][3] + pb4.w;
        float ps = y0 + y1 + y2 + y3;
        float pq = y0*y0 + y1*y1 + y2*y2 + y3*y3;
        #pragma unroll
        for (int off = 1; off < 32; off <<= 1) {    // reduce across 32 col-lanes
            ps += __shfl_xor(ps, off);
            pq += __shfl_xor(pq, off);
        }
        float mu = ps * (1.0f / DIM);
        float var = pq * (1.0f / DIM) - mu * mu;
        float rstd = rsqrtf(var + 1e-5f);
        if (n < N_NODES) {
            float4 o;
            o.x = (y0 - mu) * rstd * g4.x + b4.x;
            o.y = (y1 - mu) * rstd * g4.y + b4.y;
            o.z = (y2 - mu) * rstd * g4.z + b4.z;
            o.w = (y3 - mu) * rstd * g4.w + b4.w;
            *(float4*)(out + (size_t)n * DIM + d0) = o;
        }
    }
}

extern "C" void kernel_launch(void* const* d_in, const int* in_sizes, int n_in,
                              void* d_out, int out_size, void* d_ws, size_t ws_size,
                              hipStream_t stream) {
    const float* x       = (const float*)d_in[0];
    const int*   ei      = (const int*)  d_in[1];
    const float* ea      = (const float*)d_in[2];
    const float* align_w = (const float*)d_in[3];
    const float* align_b = (const float*)d_in[4];
    const float* value_w = (const float*)d_in[5];
    const float* value_b = (const float*)d_in[6];
    const float* proj_w  = (const float*)d_in[7];
    const float* proj_b  = (const float*)d_in[8];
    const float* ln_g    = (const float*)d_in[9];
    const float* ln_b    = (const float*)d_in[10];
    float* out = (float*)d_out;
    float* ws  = (float*)d_ws;

    // workspace layout (floats): total 16.8M floats = 67.2 MB
    float* Vx      = ws;                    // N*D   = 6,400,000
    float* a_dst   = ws + 6400000;          // N*H   =   200,000
    float* a_src   = ws + 6600000;          // N*H   =   200,000
    float* scores  = ws + 6800000;          // E*H   = 3,200,000
    float* maxv    = ws + 10000000;         // N*H   =   200,000
    float* sumv    = ws + 10200000;         // N*H   =   200,000
    float* context = ws + 10400000;         // N*D   = 6,400,000

    k_init<<<4096, 256, 0, stream>>>(maxv, sumv, context);
    k_node_pre<<<(N_NODES + 31) / 32, 128, 0, stream>>>(
        x, value_w, value_b, align_w, Vx, a_dst, a_src);
    k_edge_scores<<<N_EDGES / 16 / 16, 256, 0, stream>>>(
        ea, ei, align_w, align_b, a_dst, a_src, scores, maxv);
    k_exp_sum<<<N_EDGES / 256, 256, 0, stream>>>(ei, scores, maxv, sumv);
    k_scatter<<<N_EDGES / 8, 256, 0, stream>>>(ei, scores, sumv, Vx, context);
    k_final<<<(N_NODES + 31) / 32, 128, 0, stream>>>(
        x, context, proj_w, proj_b, ln_g, ln_b, out);
}

// Round 2
// 446.045 us; speedup vs baseline: 3.9461x; 3.9461x over previous
//
#include <hip/hip_runtime.h>
#include <math.h>

#define N_NODES 50000
#define N_EDGES 800000
#define DIM 128
#define EDIM 64
#define NH 4

__global__ __launch_bounds__(256) void k_init(int* cnt, int* cursor) {
    int i = blockIdx.x * 256 + threadIdx.x;
    if (i < N_NODES) { cnt[i] = 0; cursor[i] = 0; }
}

// 32 nodes/block, 128 threads. Vx = x@value_w + value_b; per-node score halves:
// a_dst = x@aw[0:128], a_src = x@aw[128:256].
__global__ __launch_bounds__(128) void k_node_pre(
    const float* __restrict__ x, const float* __restrict__ vw, const float* __restrict__ vb,
    const float* __restrict__ aw, float* __restrict__ Vx,
    float* __restrict__ a_dst, float* __restrict__ a_src) {
    __shared__ float xs[32][129];
    int t = threadIdx.x;
    int nb = blockIdx.x * 32;
    #pragma unroll
    for (int i = 0; i < 8; ++i) {
        int idx = i * 128 + t;
        int m = idx >> 5, k4 = idx & 31;
        int n = nb + m;
        float4 v = make_float4(0.f, 0.f, 0.f, 0.f);
        if (n < N_NODES) v = *(const float4*)(x + (size_t)n * DIM + k4 * 4);
        xs[m][k4*4+0] = v.x; xs[m][k4*4+1] = v.y; xs[m][k4*4+2] = v.z; xs[m][k4*4+3] = v.w;
    }
    __syncthreads();
    int c = t & 31, mg = t >> 5;
    int d0 = c * 4, m0 = mg * 8;
    float acc[8][4];
    #pragma unroll
    for (int j = 0; j < 8; ++j) { acc[j][0]=0.f; acc[j][1]=0.f; acc[j][2]=0.f; acc[j][3]=0.f; }
    for (int k = 0; k < DIM; ++k) {
        float4 w = *(const float4*)(vw + (size_t)k * DIM + d0);
        #pragma unroll
        for (int j = 0; j < 8; ++j) {
            float xv = xs[m0 + j][k];
            acc[j][0] += xv * w.x; acc[j][1] += xv * w.y;
            acc[j][2] += xv * w.z; acc[j][3] += xv * w.w;
        }
    }
    float4 vb4 = *(const float4*)(vb + d0);
    #pragma unroll
    for (int j = 0; j < 8; ++j) {
        int n = nb + m0 + j;
        if (n < N_NODES) {
            float4 o = make_float4(acc[j][0]+vb4.x, acc[j][1]+vb4.y,
                                   acc[j][2]+vb4.z, acc[j][3]+vb4.w);
            *(float4*)(Vx + (size_t)n * DIM + d0) = o;
        }
    }
    #pragma unroll
    for (int oo = 0; oo < 2; ++oo) {
        int o = t * 2 + oo;
        int m = o >> 3, jj = o & 7, p = jj >> 2, h = jj & 3;
        float s = 0.f;
        for (int k = 0; k < DIM; ++k) s += xs[m][k] * aw[(size_t)(p * DIM + k) * NH + h];
        int n = nb + m;
        if (n < N_NODES) { (p ? a_src : a_dst)[(size_t)n * NH + h] = s; }
    }
}

// 16 lanes/edge: coalesced edge_attr read + shuffle-reduced 64-wide dot per head;
// scores[E,4] = edge part + node parts + bias. No atomics.
__global__ __launch_bounds__(256) void k_edge_scores(
    const float* __restrict__ ea, const int* __restrict__ ei,
    const float* __restrict__ aw, const float* __restrict__ ab,
    const float* __restrict__ a_dst, const float* __restrict__ a_src,
    float* __restrict__ scores) {
    __shared__ float s_awe[256];
    __shared__ float s_b[4];
    int t = threadIdx.x;
    s_awe[t] = aw[1024 + t];
    if (t < 4) s_b[t] = ab[t];
    __syncthreads();
    int l = t & 15, g = t >> 4;
    for (int e = blockIdx.x * 16 + g; e < N_EDGES; e += gridDim.x * 16) {
        float4 v = *(const float4*)(ea + (size_t)e * EDIM + l * 4);
        float vv[4] = {v.x, v.y, v.z, v.w};
        float p[4] = {0.f, 0.f, 0.f, 0.f};
        #pragma unroll
        for (int j = 0; j < 4; ++j)
            #pragma unroll
            for (int h = 0; h < NH; ++h)
                p[h] += vv[j] * s_awe[(l*4+j)*4 + h];
        #pragma unroll
        for (int off = 1; off < 16; off <<= 1) {
            #pragma unroll
            for (int h = 0; h < NH; ++h) p[h] += __shfl_xor(p[h], off);
        }
        if (l == 0) {
            int row = ei[e], col = ei[N_EDGES + e];
            float4 ad  = *(const float4*)(a_dst + (size_t)row * NH);
            float4 as_ = *(const float4*)(a_src + (size_t)col * NH);
            *(float4*)(scores + (size_t)e * 4) = make_float4(
                p[0] + ad.x + as_.x + s_b[0], p[1] + ad.y + as_.y + s_b[1],
                p[2] + ad.z + as_.z + s_b[2], p[3] + ad.w + as_.w + s_b[3]);
        }
    }
}

__global__ __launch_bounds__(256) void k_hist(const int* __restrict__ ei, int* cnt) {
    int e = blockIdx.x * 256 + threadIdx.x;
    if (e < N_EDGES) atomicAdd(&cnt[ei[e]], 1);
}

// single-block exclusive scan of cnt[50000] -> base; base[N]=E
__global__ __launch_bounds__(1024) void k_scan(const int* __restrict__ cnt, int* __restrict__ base) {
    __shared__ int wsum[16];
    __shared__ int carry_s;
    int t = threadIdx.x;
    int lane = t & 63, w = t >> 6;
    if (t == 0) carry_s = 0;
    __syncthreads();
    for (int start = 0; start < N_NODES; start += 1024) {
        int i = start + t;
        int v = (i < N_NODES) ? cnt[i] : 0;
        int s = v;
        #pragma unroll
        for (int off = 1; off < 64; off <<= 1) {
            int u = __shfl_up(s, off);
            if (lane >= off) s += u;
        }
        if (lane == 63) wsum[w] = s;
        __syncthreads();
        if (w == 0 && lane < 16) {
            int ws = wsum[lane];
            #pragma unroll
            for (int off = 1; off < 16; off <<= 1) {
                int u = __shfl_up(ws, off);
                if (lane >= off) ws += u;
            }
            wsum[lane] = ws;
        }
        __syncthreads();
        int wbase = (w == 0) ? 0 : wsum[w - 1];
        int carry = carry_s;
        if (i < N_NODES) base[i] = carry + wbase + s - v;
        __syncthreads();
        if (t == 1023) carry_s = carry + wsum[15];
        __syncthreads();
    }
    if (t == 0) base[N_NODES] = N_EDGES;
}

__global__ __launch_bounds__(256) void k_scatter_idx(
    const int* __restrict__ ei, const int* __restrict__ base,
    int* cursor, int* __restrict__ eorder) {
    int e = blockIdx.x * 256 + threadIdx.x;
    if (e < N_EDGES) {
        int row = ei[e];
        int pos = base[row] + atomicAdd(&cursor[row], 1);
        eorder[pos] = e;
    }
}

// One wave per 8 nodes, 32 nodes/block. Per node: CSR softmax (online max+sum,
// shuffle-combined), register accumulate of alpha*Vx[col] (2 dims/lane) -> LDS;
// then block-wide proj GEMM + residual + LN. No atomics, no context HBM trip.
__global__ __launch_bounds__(256) void k_node_fused(
    const int* __restrict__ ei, const int* __restrict__ base, const int* __restrict__ eorder,
    const float* __restrict__ scores, const float* __restrict__ Vx,
    const float* __restrict__ x, const float* __restrict__ pw, const float* __restrict__ pb,
    const float* __restrict__ lg, const float* __restrict__ lb, float* __restrict__ out) {
    __shared__ float cs[32][130];
    int t = threadIdx.x;
    int lane = t & 63, w = t >> 6;
    int nb = blockIdx.x * 32;
    int h = lane & 3, g = lane >> 2, hh = lane >> 4;
    for (int j = 0; j < 8; ++j) {
        int m = w * 8 + j;
        int n = nb + m;
        float acc0 = 0.f, acc1 = 0.f;
        if (n < N_NODES) {
            int s0 = base[n], s1 = base[n + 1];
            // pass A: 16 edge-groups x 4 head-lanes, online max+sum
            float mx = -1e30f, sum = 0.f;
            for (int i = s0 + g; i < s1; i += 16) {
                int e = eorder[i];
                float s = scores[(size_t)e * 4 + h];
                float mn = fmaxf(mx, s);
                sum = sum * __expf(mx - mn) + __expf(s - mn);
                mx = mn;
            }
            #pragma unroll
            for (int off = 4; off < 64; off <<= 1) {
                float mo = __shfl_xor(mx, off);
                float so = __shfl_xor(sum, off);
                float mn = fmaxf(mx, mo);
                sum = sum * __expf(mx - mn) + so * __expf(mo - mn);
                mx = mn;
            }
            float mh = __shfl(mx, hh);
            float invh = __shfl(1.0f / (sum + 1e-8f), hh);
            // pass B: lane l owns dims 2l,2l+1 (head = l>>4)
            for (int i = s0; i < s1; ++i) {
                int e = eorder[i];
                int col = ei[N_EDGES + e];
                float sc = scores[(size_t)e * 4 + hh];
                float a = __expf(sc - mh) * invh;
                float2 v = *(const float2*)(Vx + (size_t)col * DIM + lane * 2);
                acc0 += v.x * a; acc1 += v.y * a;
            }
        }
        cs[m][lane * 2]     = acc0;
        cs[m][lane * 2 + 1] = acc1;
    }
    __syncthreads();
    // projection + residual + LN; wave mg handles nodes mg*8..+7, 2 dims/thread
    int d0 = (t & 63) * 2, mg = t >> 6;
    int m0 = mg * 8;
    float acc[8][2];
    #pragma unroll
    for (int j = 0; j < 8; ++j) { acc[j][0] = 0.f; acc[j][1] = 0.f; }
    for (int k = 0; k < DIM; ++k) {
        float2 wv = *(const float2*)(pw + (size_t)k * DIM + d0);
        #pragma unroll
        for (int j = 0; j < 8; ++j) {
            float cv = cs[m0 + j][k];
            acc[j][0] += cv * wv.x; acc[j][1] += cv * wv.y;
        }
    }
    float2 pb2 = *(const float2*)(pb + d0);
    float2 g2  = *(const float2*)(lg + d0);
    float2 b2  = *(const float2*)(lb + d0);
    #pragma unroll
    for (int j = 0; j < 8; ++j) {
        int n = nb + m0 + j;
        float2 xv = make_float2(0.f, 0.f);
        if (n < N_NODES) xv = *(const float2*)(x + (size_t)n * DIM + d0);
        float y0 = xv.x + acc[j][0] + pb2.x;
        float y1 = xv.y + acc[j][1] + pb2.y;
        float ps = y0 + y1, pq = y0*y0 + y1*y1;
        #pragma unroll
        for (int off = 1; off < 64; off <<= 1) {
            ps += __shfl_xor(ps, off);
            pq += __shfl_xor(pq, off);
        }
        float mu = ps * (1.0f / DIM);
        float var = pq * (1.0f / DIM) - mu * mu;
        float rstd = rsqrtf(var + 1e-5f);
        if (n < N_NODES) {
            float2 o;
            o.x = (y0 - mu) * rstd * g2.x + b2.x;
            o.y = (y1 - mu) * rstd * g2.y + b2.y;
            *(float2*)(out + (size_t)n * DIM + d0) = o;
        }
    }
}

extern "C" void kernel_launch(void* const* d_in, const int* in_sizes, int n_in,
                              void* d_out, int out_size, void* d_ws, size_t ws_size,
                              hipStream_t stream) {
    const float* x       = (const float*)d_in[0];
    const int*   ei      = (const int*)  d_in[1];
    const float* ea      = (const float*)d_in[2];
    const float* align_w = (const float*)d_in[3];
    const float* align_b = (const float*)d_in[4];
    const float* value_w = (const float*)d_in[5];
    const float* value_b = (const float*)d_in[6];
    const float* proj_w  = (const float*)d_in[7];
    const float* proj_b  = (const float*)d_in[8];
    const float* ln_g    = (const float*)d_in[9];
    const float* ln_b    = (const float*)d_in[10];
    float* out = (float*)d_out;
    float* ws  = (float*)d_ws;

    // workspace (floats): total ~10.96M floats = 43.8 MB
    float* Vx     = ws;                      // 6,400,000
    float* a_dst  = ws + 6400000;            //   200,000
    float* a_src  = ws + 6600000;            //   200,000
    float* scores = ws + 6800000;            // 3,200,000
    int*   cnt    = (int*)(ws + 10000000);   //    50,000
    int*   base   = (int*)(ws + 10050000);   //    50,001
    int*   cursor = (int*)(ws + 10100001);   //    50,000
    int*   eorder = (int*)(ws + 10150001);   //   800,000

    k_init<<<(N_NODES + 255) / 256, 256, 0, stream>>>(cnt, cursor);
    k_node_pre<<<(N_NODES + 31) / 32, 128, 0, stream>>>(
        x, value_w, value_b, align_w, Vx, a_dst, a_src);
    k_edge_scores<<<N_EDGES / 16 / 16, 256, 0, stream>>>(
        ea, ei, align_w, align_b, a_dst, a_src, scores);
    k_hist<<<(N_EDGES + 255) / 256, 256, 0, stream>>>(ei, cnt);
    k_scan<<<1, 1024, 0, stream>>>(cnt, base);
    k_scatter_idx<<<(N_EDGES + 255) / 256, 256, 0, stream>>>(ei, base, cursor, eorder);
    k_node_fused<<<(N_NODES + 31) / 32, 256, 0, stream>>>(
        ei, base, eorder, scores, Vx, x, proj_w, proj_b, ln_g, ln_b, out);
}

// Round 3
// 311.015 us; speedup vs baseline: 5.6594x; 1.4342x over previous
//
#include <hip/hip_runtime.h>
#include <math.h>

#define N_NODES 50000
#define N_EDGES 800000
#define DIM 128
#define EDIM 64
#define NH 4
#define SCAN_BLOCKS ((N_NODES + 255) / 256)   // 196

__global__ __launch_bounds__(256) void k_init(int* cnt, int* cursor) {
    int i = blockIdx.x * 256 + threadIdx.x;
    if (i < N_NODES) { cnt[i] = 0; cursor[i] = 0; }
}

__global__ __launch_bounds__(256) void k_hist(const int* __restrict__ ei, int* cnt) {
    int e = blockIdx.x * 256 + threadIdx.x;
    if (e < N_EDGES) atomicAdd(&cnt[ei[e]], 1);
}

// per-block exclusive scan (256 elems); block totals to bsum
__global__ __launch_bounds__(256) void k_scan_blk(
    const int* __restrict__ cnt, int* __restrict__ base, int* __restrict__ bsum) {
    __shared__ int wtot[4];
    int t = threadIdx.x, lane = t & 63, w = t >> 6;
    int i = blockIdx.x * 256 + t;
    int v = (i < N_NODES) ? cnt[i] : 0;
    int s = v;
    #pragma unroll
    for (int off = 1; off < 64; off <<= 1) {
        int u = __shfl_up(s, off);
        if (lane >= off) s += u;
    }
    if (lane == 63) wtot[w] = s;
    __syncthreads();
    int prefix = 0;
    for (int k = 0; k < w; ++k) prefix += wtot[k];
    if (i < N_NODES) base[i] = prefix + s - v;
    if (t == 255) bsum[blockIdx.x] = prefix + s;
}

// add scanned block offsets; each block redundantly reduces bsum[0..b)
__global__ __launch_bounds__(256) void k_scan_add(int* __restrict__ base,
                                                 const int* __restrict__ bsum) {
    __shared__ int red[4];
    int t = threadIdx.x, lane = t & 63, w = t >> 6, b = blockIdx.x;
    int val = (t < b && t < SCAN_BLOCKS) ? bsum[t] : 0;
    #pragma unroll
    for (int off = 1; off < 64; off <<= 1) val += __shfl_xor(val, off);
    if (lane == 0) red[w] = val;
    __syncthreads();
    int boff = red[0] + red[1] + red[2] + red[3];
    int i = b * 256 + t;
    if (i < N_NODES) base[i] += boff;
    if (i == 0) base[N_NODES] = N_EDGES;
}

// 32 nodes/block, 128 threads. Vx = x@value_w + value_b; per-node score halves.
__global__ __launch_bounds__(128) void k_node_pre(
    const float* __restrict__ x, const float* __restrict__ vw, const float* __restrict__ vb,
    const float* __restrict__ aw, float* __restrict__ Vx,
    float* __restrict__ a_dst, float* __restrict__ a_src) {
    __shared__ float xs[32][129];
    int t = threadIdx.x;
    int nb = blockIdx.x * 32;
    #pragma unroll
    for (int i = 0; i < 8; ++i) {
        int idx = i * 128 + t;
        int m = idx >> 5, k4 = idx & 31;
        int n = nb + m;
        float4 v = make_float4(0.f, 0.f, 0.f, 0.f);
        if (n < N_NODES) v = *(const float4*)(x + (size_t)n * DIM + k4 * 4);
        xs[m][k4*4+0] = v.x; xs[m][k4*4+1] = v.y; xs[m][k4*4+2] = v.z; xs[m][k4*4+3] = v.w;
    }
    __syncthreads();
    int c = t & 31, mg = t >> 5;
    int d0 = c * 4, m0 = mg * 8;
    float acc[8][4];
    #pragma unroll
    for (int j = 0; j < 8; ++j) { acc[j][0]=0.f; acc[j][1]=0.f; acc[j][2]=0.f; acc[j][3]=0.f; }
    for (int k = 0; k < DIM; ++k) {
        float4 w = *(const float4*)(vw + (size_t)k * DIM + d0);
        #pragma unroll
        for (int j = 0; j < 8; ++j) {
            float xv = xs[m0 + j][k];
            acc[j][0] += xv * w.x; acc[j][1] += xv * w.y;
            acc[j][2] += xv * w.z; acc[j][3] += xv * w.w;
        }
    }
    float4 vb4 = *(const float4*)(vb + d0);
    #pragma unroll
    for (int j = 0; j < 8; ++j) {
        int n = nb + m0 + j;
        if (n < N_NODES) {
            float4 o = make_float4(acc[j][0]+vb4.x, acc[j][1]+vb4.y,
                                   acc[j][2]+vb4.z, acc[j][3]+vb4.w);
            *(float4*)(Vx + (size_t)n * DIM + d0) = o;
        }
    }
    #pragma unroll
    for (int oo = 0; oo < 2; ++oo) {
        int o = t * 2 + oo;
        int m = o >> 3, jj = o & 7, p = jj >> 2, h = jj & 3;
        float s = 0.f;
        for (int k = 0; k < DIM; ++k) s += xs[m][k] * aw[(size_t)(p * DIM + k) * NH + h];
        int n = nb + m;
        if (n < N_NODES) { (p ? a_src : a_dst)[(size_t)n * NH + h] = s; }
    }
}

// 16 lanes/edge; writes scores and src col DIRECTLY INTO CSR ORDER via cursor.
__global__ __launch_bounds__(256) void k_edge_scores(
    const float* __restrict__ ea, const int* __restrict__ ei,
    const float* __restrict__ aw, const float* __restrict__ ab,
    const float* __restrict__ a_dst, const float* __restrict__ a_src,
    const int* __restrict__ base, int* cursor,
    float* __restrict__ sscores, int* __restrict__ ecol) {
    __shared__ float s_awe[256];
    __shared__ float s_b[4];
    int t = threadIdx.x;
    s_awe[t] = aw[1024 + t];
    if (t < 4) s_b[t] = ab[t];
    __syncthreads();
    int l = t & 15, g = t >> 4;
    for (int e = blockIdx.x * 16 + g; e < N_EDGES; e += gridDim.x * 16) {
        float4 v = *(const float4*)(ea + (size_t)e * EDIM + l * 4);
        float vv[4] = {v.x, v.y, v.z, v.w};
        float p[4] = {0.f, 0.f, 0.f, 0.f};
        #pragma unroll
        for (int j = 0; j < 4; ++j)
            #pragma unroll
            for (int h = 0; h < NH; ++h)
                p[h] += vv[j] * s_awe[(l*4+j)*4 + h];
        #pragma unroll
        for (int off = 1; off < 16; off <<= 1) {
            #pragma unroll
            for (int h = 0; h < NH; ++h) p[h] += __shfl_xor(p[h], off);
        }
        if (l == 0) {
            int row = ei[e], col = ei[N_EDGES + e];
            float4 ad  = *(const float4*)(a_dst + (size_t)row * NH);
            float4 as_ = *(const float4*)(a_src + (size_t)col * NH);
            int pos = base[row] + atomicAdd(&cursor[row], 1);
            *(float4*)(sscores + (size_t)pos * 4) = make_float4(
                p[0] + ad.x + as_.x + s_b[0], p[1] + ad.y + as_.y + s_b[1],
                p[2] + ad.z + as_.z + s_b[2], p[3] + ad.w + as_.w + s_b[3]);
            ecol[pos] = col;
        }
    }
}

// 16 nodes/block, 256 threads; wave handles 4 nodes. CSR softmax (coalesced
// pass A), x4-unrolled register accumulate of alpha*Vx (pass B), then fused
// proj + residual + LN. No float atomics anywhere.
__global__ __launch_bounds__(256) void k_node_fused(
    const int* __restrict__ ecol, const int* __restrict__ base,
    const float* __restrict__ sscores, const float* __restrict__ Vx,
    const float* __restrict__ x, const float* __restrict__ pw, const float* __restrict__ pb,
    const float* __restrict__ lg, const float* __restrict__ lb, float* __restrict__ out) {
    __shared__ float cs[16][130];
    int t = threadIdx.x;
    int lane = t & 63, w = t >> 6;
    int nb = blockIdx.x * 16;
    int h = lane & 3, g = lane >> 2, hh = lane >> 4;
    for (int j = 0; j < 4; ++j) {
        int m = w * 4 + j;
        int n = nb + m;
        float acc0 = 0.f, acc1 = 0.f;
        if (n < N_NODES) {
            int s0 = base[n], s1 = base[n + 1];
            // pass A: coalesced — lane (g,h) reads sscores[(s0+g)*4+h] = s0*4+lane
            float mx = -1e30f, sum = 0.f;
            for (int i = s0 + g; i < s1; i += 16) {
                float s = sscores[(size_t)i * 4 + h];
                float mn = fmaxf(mx, s);
                sum = sum * __expf(mx - mn) + __expf(s - mn);
                mx = mn;
            }
            #pragma unroll
            for (int off = 4; off < 64; off <<= 1) {
                float mo = __shfl_xor(mx, off);
                float so = __shfl_xor(sum, off);
                float mn = fmaxf(mx, mo);
                sum = sum * __expf(mx - mn) + so * __expf(mo - mn);
                mx = mn;
            }
            float mh = __shfl(mx, hh);
            float invh = __shfl(1.0f / (sum + 1e-8f), hh);
            // pass B: lane owns dims 2l,2l+1 (head hh); 4 edges in flight
            int i = s0;
            for (; i + 3 < s1; i += 4) {
                int c0 = ecol[i], c1 = ecol[i+1], c2 = ecol[i+2], c3 = ecol[i+3];
                float t0 = sscores[(size_t)i * 4 + hh];
                float t1 = sscores[(size_t)(i+1) * 4 + hh];
                float t2 = sscores[(size_t)(i+2) * 4 + hh];
                float t3 = sscores[(size_t)(i+3) * 4 + hh];
                float2 v0 = *(const float2*)(Vx + (size_t)c0 * DIM + lane * 2);
                float2 v1 = *(const float2*)(Vx + (size_t)c1 * DIM + lane * 2);
                float2 v2 = *(const float2*)(Vx + (size_t)c2 * DIM + lane * 2);
                float2 v3 = *(const float2*)(Vx + (size_t)c3 * DIM + lane * 2);
                float a0 = __expf(t0 - mh) * invh;
                float a1 = __expf(t1 - mh) * invh;
                float a2 = __expf(t2 - mh) * invh;
                float a3 = __expf(t3 - mh) * invh;
                acc0 += v0.x*a0; acc1 += v0.y*a0;
                acc0 += v1.x*a1; acc1 += v1.y*a1;
                acc0 += v2.x*a2; acc1 += v2.y*a2;
                acc0 += v3.x*a3; acc1 += v3.y*a3;
            }
            for (; i < s1; ++i) {
                int c = ecol[i];
                float sc = sscores[(size_t)i * 4 + hh];
                float a = __expf(sc - mh) * invh;
                float2 v = *(const float2*)(Vx + (size_t)c * DIM + lane * 2);
                acc0 += v.x * a; acc1 += v.y * a;
            }
        }
        cs[m][lane * 2]     = acc0;
        cs[m][lane * 2 + 1] = acc1;
    }
    __syncthreads();
    // proj + residual + LN: wave mg handles nodes mg*4..+3, 2 dims/thread
    int d0 = (t & 63) * 2, mg = t >> 6;
    int m0 = mg * 4;
    float acc[4][2];
    #pragma unroll
    for (int j = 0; j < 4; ++j) { acc[j][0] = 0.f; acc[j][1] = 0.f; }
    for (int k = 0; k < DIM; ++k) {
        float2 wv = *(const float2*)(pw + (size_t)k * DIM + d0);
        #pragma unroll
        for (int j = 0; j < 4; ++j) {
            float cv = cs[m0 + j][k];
            acc[j][0] += cv * wv.x; acc[j][1] += cv * wv.y;
        }
    }
    float2 pb2 = *(const float2*)(pb + d0);
    float2 g2  = *(const float2*)(lg + d0);
    float2 b2  = *(const float2*)(lb + d0);
    #pragma unroll
    for (int j = 0; j < 4; ++j) {
        int n = nb + m0 + j;
        float2 xv = make_float2(0.f, 0.f);
        if (n < N_NODES) xv = *(const float2*)(x + (size_t)n * DIM + d0);
        float y0 = xv.x + acc[j][0] + pb2.x;
        float y1 = xv.y + acc[j][1] + pb2.y;
        float ps = y0 + y1, pq = y0*y0 + y1*y1;
        #pragma unroll
        for (int off = 1; off < 64; off <<= 1) {
            ps += __shfl_xor(ps, off);
            pq += __shfl_xor(pq, off);
        }
        float mu = ps * (1.0f / DIM);
        float var = pq * (1.0f / DIM) - mu * mu;
        float rstd = rsqrtf(var + 1e-5f);
        if (n < N_NODES) {
            float2 o;
            o.x = (y0 - mu) * rstd * g2.x + b2.x;
            o.y = (y1 - mu) * rstd * g2.y + b2.y;
            *(float2*)(out + (size_t)n * DIM + d0) = o;
        }
    }
}

extern "C" void kernel_launch(void* const* d_in, const int* in_sizes, int n_in,
                              void* d_out, int out_size, void* d_ws, size_t ws_size,
                              hipStream_t stream) {
    const float* x       = (const float*)d_in[0];
    const int*   ei      = (const int*)  d_in[1];
    const float* ea      = (const float*)d_in[2];
    const float* align_w = (const float*)d_in[3];
    const float* align_b = (const float*)d_in[4];
    const float* value_w = (const float*)d_in[5];
    const float* value_b = (const float*)d_in[6];
    const float* proj_w  = (const float*)d_in[7];
    const float* proj_b  = (const float*)d_in[8];
    const float* ln_g    = (const float*)d_in[9];
    const float* ln_b    = (const float*)d_in[10];
    float* out = (float*)d_out;
    float* ws  = (float*)d_ws;

    // workspace (float slots): ~10.96M floats = 43.9 MB
    float* Vx      = ws;                       // 6,400,000
    float* a_dst   = ws + 6400000;             //   200,000
    float* a_src   = ws + 6600000;             //   200,000
    float* sscores = ws + 6800000;             // 3,200,000 (CSR-ordered, [pos][4])
    int*   ecol    = (int*)(ws + 10000000);    //   800,000 (CSR-ordered src col)
    int*   cnt     = (int*)(ws + 10800000);    //    50,000
    int*   base    = (int*)(ws + 10850000);    //    50,001
    int*   cursor  = (int*)(ws + 10900001);    //    50,000
    int*   bsum    = (int*)(ws + 10950001);    //       256

    k_init<<<SCAN_BLOCKS, 256, 0, stream>>>(cnt, cursor);
    k_hist<<<(N_EDGES + 255) / 256, 256, 0, stream>>>(ei, cnt);
    k_scan_blk<<<SCAN_BLOCKS, 256, 0, stream>>>(cnt, base, bsum);
    k_scan_add<<<SCAN_BLOCKS, 256, 0, stream>>>(base, bsum);
    k_node_pre<<<(N_NODES + 31) / 32, 128, 0, stream>>>(
        x, value_w, value_b, align_w, Vx, a_dst, a_src);
    k_edge_scores<<<N_EDGES / 16 / 16, 256, 0, stream>>>(
        ea, ei, align_w, align_b, a_dst, a_src, base, cursor, sscores, ecol);
    k_node_fused<<<(N_NODES + 15) / 16, 256, 0, stream>>>(
        ecol, base, sscores, Vx, x, proj_w, proj_b, ln_g, ln_b, out);
}

// Round 4
// 310.879 us; speedup vs baseline: 5.6618x; 1.0004x over previous
//
#include <hip/hip_runtime.h>
#include <hip/hip_bf16.h>
#include <math.h>

#define N_NODES 50000
#define N_EDGES 800000
#define DIM 128
#define EDIM 64
#define NH 4
#define SCAN_BLOCKS ((N_NODES + 255) / 256)   // 196

__global__ __launch_bounds__(256) void k_init(int* cnt, int* cursor) {
    int i = blockIdx.x * 256 + threadIdx.x;
    if (i < N_NODES) { cnt[i] = 0; cursor[i] = 0; }
}

__global__ __launch_bounds__(256) void k_hist(const int* __restrict__ ei, int* cnt) {
    int e = blockIdx.x * 256 + threadIdx.x;
    if (e < N_EDGES) atomicAdd(&cnt[ei[e]], 1);
}

// per-block exclusive scan (256 elems); block totals to bsum
__global__ __launch_bounds__(256) void k_scan_blk(
    const int* __restrict__ cnt, int* __restrict__ base, int* __restrict__ bsum) {
    __shared__ int wtot[4];
    int t = threadIdx.x, lane = t & 63, w = t >> 6;
    int i = blockIdx.x * 256 + t;
    int v = (i < N_NODES) ? cnt[i] : 0;
    int s = v;
    #pragma unroll
    for (int off = 1; off < 64; off <<= 1) {
        int u = __shfl_up(s, off);
        if (lane >= off) s += u;
    }
    if (lane == 63) wtot[w] = s;
    __syncthreads();
    int prefix = 0;
    for (int k = 0; k < w; ++k) prefix += wtot[k];
    if (i < N_NODES) base[i] = prefix + s - v;
    if (t == 255) bsum[blockIdx.x] = prefix + s;
}

// add scanned block offsets; each block redundantly reduces bsum[0..b)
__global__ __launch_bounds__(256) void k_scan_add(int* __restrict__ base,
                                                 const int* __restrict__ bsum) {
    __shared__ int red[4];
    int t = threadIdx.x, lane = t & 63, w = t >> 6, b = blockIdx.x;
    int val = (t < b && t < SCAN_BLOCKS) ? bsum[t] : 0;
    #pragma unroll
    for (int off = 1; off < 64; off <<= 1) val += __shfl_xor(val, off);
    if (lane == 0) red[w] = val;
    __syncthreads();
    int boff = red[0] + red[1] + red[2] + red[3];
    int i = b * 256 + t;
    if (i < N_NODES) base[i] += boff;
    if (i == 0) base[N_NODES] = N_EDGES;
}

// 1 thread/edge: CSR position via int atomic; writes epos (edge->slot) and
// ecol (CSR-ordered src col). Removes atomics from the hot edge kernel.
__global__ __launch_bounds__(256) void k_scatter_idx(
    const int* __restrict__ ei, const int* __restrict__ base,
    int* cursor, int* __restrict__ epos, int* __restrict__ ecol) {
    int e = blockIdx.x * 256 + threadIdx.x;
    if (e < N_EDGES) {
        int row = ei[e];
        int pos = base[row] + atomicAdd(&cursor[row], 1);
        epos[e] = pos;
        ecol[pos] = ei[N_EDGES + e];
    }
}

// 32 nodes/block, 128 threads. Vx(bf16) = x@value_w + value_b; per-node score
// halves: a_dst = x@aw[0:128] + align_b (bias folded), a_src = x@aw[128:256].
__global__ __launch_bounds__(128) void k_node_pre(
    const float* __restrict__ x, const float* __restrict__ vw, const float* __restrict__ vb,
    const float* __restrict__ aw, const float* __restrict__ ab,
    unsigned int* __restrict__ Vxb,          // bf16x2 packed, 64 words per node
    float* __restrict__ a_dst, float* __restrict__ a_src) {
    __shared__ float xs[32][129];
    int t = threadIdx.x;
    int nb = blockIdx.x * 32;
    #pragma unroll
    for (int i = 0; i < 8; ++i) {
        int idx = i * 128 + t;
        int m = idx >> 5, k4 = idx & 31;
        int n = nb + m;
        float4 v = make_float4(0.f, 0.f, 0.f, 0.f);
        if (n < N_NODES) v = *(const float4*)(x + (size_t)n * DIM + k4 * 4);
        xs[m][k4*4+0] = v.x; xs[m][k4*4+1] = v.y; xs[m][k4*4+2] = v.z; xs[m][k4*4+3] = v.w;
    }
    __syncthreads();
    int c = t & 31, mg = t >> 5;
    int d0 = c * 4, m0 = mg * 8;
    float acc[8][4];
    #pragma unroll
    for (int j = 0; j < 8; ++j) { acc[j][0]=0.f; acc[j][1]=0.f; acc[j][2]=0.f; acc[j][3]=0.f; }
    for (int k = 0; k < DIM; ++k) {
        float4 w = *(const float4*)(vw + (size_t)k * DIM + d0);
        #pragma unroll
        for (int j = 0; j < 8; ++j) {
            float xv = xs[m0 + j][k];
            acc[j][0] += xv * w.x; acc[j][1] += xv * w.y;
            acc[j][2] += xv * w.z; acc[j][3] += xv * w.w;
        }
    }
    float4 vb4 = *(const float4*)(vb + d0);
    #pragma unroll
    for (int j = 0; j < 8; ++j) {
        int n = nb + m0 + j;
        if (n < N_NODES) {
            __hip_bfloat162 p0 = __float22bfloat162_rn(
                make_float2(acc[j][0]+vb4.x, acc[j][1]+vb4.y));
            __hip_bfloat162 p1 = __float22bfloat162_rn(
                make_float2(acc[j][2]+vb4.z, acc[j][3]+vb4.w));
            uint2 u;
            u.x = *reinterpret_cast<unsigned int*>(&p0);
            u.y = *reinterpret_cast<unsigned int*>(&p1);
            *(uint2*)(Vxb + (size_t)n * 64 + c * 2) = u;
        }
    }
    #pragma unroll
    for (int oo = 0; oo < 2; ++oo) {
        int o = t * 2 + oo;
        int m = o >> 3, jj = o & 7, p = jj >> 2, h = jj & 3;
        float s = p ? 0.f : ab[h];
        for (int k = 0; k < DIM; ++k) s += xs[m][k] * aw[(size_t)(p * DIM + k) * NH + h];
        int n = nb + m;
        if (n < N_NODES) { (p ? a_src : a_dst)[(size_t)n * NH + h] = s; }
    }
}

// 16 lanes/edge as (quarter q, head h): lane's 16 weights live in REGISTERS
// (no LDS, no bank conflicts); reduce = 2 shuffles. Writes straight into CSR
// slot epos[e]; no atomics.
__global__ __launch_bounds__(256) void k_edge_scores(
    const float* __restrict__ ea, const int* __restrict__ ei,
    const float* __restrict__ aw,
    const float* __restrict__ a_dst, const float* __restrict__ a_src,
    const int* __restrict__ epos, float* __restrict__ sscores) {
    int t = threadIdx.x;
    int l = t & 15, g = t >> 4;
    int h = l & 3, q = l >> 2;
    float wreg[16];
    #pragma unroll
    for (int m = 0; m < 16; ++m)
        wreg[m] = aw[1024 + (q * 16 + m) * 4 + h];
    for (int e = blockIdx.x * 16 + g; e < N_EDGES; e += gridDim.x * 16) {
        const float4* eap = (const float4*)(ea + (size_t)e * EDIM + q * 16);
        float p = 0.f;
        #pragma unroll
        for (int j = 0; j < 4; ++j) {
            float4 v = eap[j];
            p += v.x * wreg[j*4+0] + v.y * wreg[j*4+1]
               + v.z * wreg[j*4+2] + v.w * wreg[j*4+3];
        }
        p += __shfl_xor(p, 4);
        p += __shfl_xor(p, 8);
        if (q == 0) {
            int row = ei[e], col = ei[N_EDGES + e];
            float s = p + a_dst[(size_t)row * NH + h] + a_src[(size_t)col * NH + h];
            int pos = epos[e];
            sscores[(size_t)pos * 4 + h] = s;
        }
    }
}

// 16 nodes/block, 256 threads; wave handles 4 nodes. CSR softmax (coalesced
// pass A), x4-unrolled bf16 Vx gather (pass B), fused proj + residual + LN.
__global__ __launch_bounds__(256) void k_node_fused(
    const int* __restrict__ ecol, const int* __restrict__ base,
    const float* __restrict__ sscores, const unsigned int* __restrict__ Vxb,
    const float* __restrict__ x, const float* __restrict__ pw, const float* __restrict__ pb,
    const float* __restrict__ lg, const float* __restrict__ lb, float* __restrict__ out) {
    __shared__ float cs[16][130];
    int t = threadIdx.x;
    int lane = t & 63, w = t >> 6;
    int nb = blockIdx.x * 16;
    int h = lane & 3, g = lane >> 2, hh = lane >> 4;
    for (int j = 0; j < 4; ++j) {
        int m = w * 4 + j;
        int n = nb + m;
        float acc0 = 0.f, acc1 = 0.f;
        if (n < N_NODES) {
            int s0 = base[n], s1 = base[n + 1];
            float mx = -1e30f, sum = 0.f;
            for (int i = s0 + g; i < s1; i += 16) {
                float s = sscores[(size_t)i * 4 + h];
                float mn = fmaxf(mx, s);
                sum = sum * __expf(mx - mn) + __expf(s - mn);
                mx = mn;
            }
            #pragma unroll
            for (int off = 4; off < 64; off <<= 1) {
                float mo = __shfl_xor(mx, off);
                float so = __shfl_xor(sum, off);
                float mn = fmaxf(mx, mo);
                sum = sum * __expf(mx - mn) + so * __expf(mo - mn);
                mx = mn;
            }
            float mh = __shfl(mx, hh);
            float invh = __shfl(1.0f / (sum + 1e-8f), hh);
            int i = s0;
            for (; i + 3 < s1; i += 4) {
                int c0 = ecol[i], c1 = ecol[i+1], c2 = ecol[i+2], c3 = ecol[i+3];
                float t0 = sscores[(size_t)i * 4 + hh];
                float t1 = sscores[(size_t)(i+1) * 4 + hh];
                float t2 = sscores[(size_t)(i+2) * 4 + hh];
                float t3 = sscores[(size_t)(i+3) * 4 + hh];
                unsigned int u0 = Vxb[(size_t)c0 * 64 + lane];
                unsigned int u1 = Vxb[(size_t)c1 * 64 + lane];
                unsigned int u2 = Vxb[(size_t)c2 * 64 + lane];
                unsigned int u3 = Vxb[(size_t)c3 * 64 + lane];
                float a0 = __expf(t0 - mh) * invh;
                float a1 = __expf(t1 - mh) * invh;
                float a2 = __expf(t2 - mh) * invh;
                float a3 = __expf(t3 - mh) * invh;
                float2 v0 = __bfloat1622float2(*reinterpret_cast<__hip_bfloat162*>(&u0));
                float2 v1 = __bfloat1622float2(*reinterpret_cast<__hip_bfloat162*>(&u1));
                float2 v2 = __bfloat1622float2(*reinterpret_cast<__hip_bfloat162*>(&u2));
                float2 v3 = __bfloat1622float2(*reinterpret_cast<__hip_bfloat162*>(&u3));
                acc0 += v0.x*a0; acc1 += v0.y*a0;
                acc0 += v1.x*a1; acc1 += v1.y*a1;
                acc0 += v2.x*a2; acc1 += v2.y*a2;
                acc0 += v3.x*a3; acc1 += v3.y*a3;
            }
            for (; i < s1; ++i) {
                int c = ecol[i];
                float sc = sscores[(size_t)i * 4 + hh];
                float a = __expf(sc - mh) * invh;
                unsigned int u = Vxb[(size_t)c * 64 + lane];
                float2 v = __bfloat1622float2(*reinterpret_cast<__hip_bfloat162*>(&u));
                acc0 += v.x * a; acc1 += v.y * a;
            }
        }
        cs[m][lane * 2]     = acc0;
        cs[m][lane * 2 + 1] = acc1;
    }
    __syncthreads();
    int d0 = (t & 63) * 2, mg = t >> 6;
    int m0 = mg * 4;
    float acc[4][2];
    #pragma unroll
    for (int j = 0; j < 4; ++j) { acc[j][0] = 0.f; acc[j][1] = 0.f; }
    for (int k = 0; k < DIM; ++k) {
        float2 wv = *(const float2*)(pw + (size_t)k * DIM + d0);
        #pragma unroll
        for (int j = 0; j < 4; ++j) {
            float cv = cs[m0 + j][k];
            acc[j][0] += cv * wv.x; acc[j][1] += cv * wv.y;
        }
    }
    float2 pb2 = *(const float2*)(pb + d0);
    float2 g2  = *(const float2*)(lg + d0);
    float2 b2  = *(const float2*)(lb + d0);
    #pragma unroll
    for (int j = 0; j < 4; ++j) {
        int n = nb + m0 + j;
        float2 xv = make_float2(0.f, 0.f);
        if (n < N_NODES) xv = *(const float2*)(x + (size_t)n * DIM + d0);
        float y0 = xv.x + acc[j][0] + pb2.x;
        float y1 = xv.y + acc[j][1] + pb2.y;
        float ps = y0 + y1, pq = y0*y0 + y1*y1;
        #pragma unroll
        for (int off = 1; off < 64; off <<= 1) {
            ps += __shfl_xor(ps, off);
            pq += __shfl_xor(pq, off);
        }
        float mu = ps * (1.0f / DIM);
        float var = pq * (1.0f / DIM) - mu * mu;
        float rstd = rsqrtf(var + 1e-5f);
        if (n < N_NODES) {
            float2 o;
            o.x = (y0 - mu) * rstd * g2.x + b2.x;
            o.y = (y1 - mu) * rstd * g2.y + b2.y;
            *(float2*)(out + (size_t)n * DIM + d0) = o;
        }
    }
}

extern "C" void kernel_launch(void* const* d_in, const int* in_sizes, int n_in,
                              void* d_out, int out_size, void* d_ws, size_t ws_size,
                              hipStream_t stream) {
    const float* x       = (const float*)d_in[0];
    const int*   ei      = (const int*)  d_in[1];
    const float* ea      = (const float*)d_in[2];
    const float* align_w = (const float*)d_in[3];
    const float* align_b = (const float*)d_in[4];
    const float* value_w = (const float*)d_in[5];
    const float* value_b = (const float*)d_in[6];
    const float* proj_w  = (const float*)d_in[7];
    const float* proj_b  = (const float*)d_in[8];
    const float* ln_g    = (const float*)d_in[9];
    const float* ln_b    = (const float*)d_in[10];
    float* out = (float*)d_out;
    float* ws  = (float*)d_ws;

    // workspace (float slots): ~8.45M floats ≈ 33.8 MB
    unsigned int* Vxb  = (unsigned int*)ws;     // 3,200,000 words (bf16 Vx)
    float* a_dst   = ws + 3200000;              //   200,000
    float* a_src   = ws + 3400000;              //   200,000
    float* sscores = ws + 3600000;              // 3,200,000 (CSR-ordered [pos][4])
    int*   ecol    = (int*)(ws + 6800000);      //   800,000
    int*   epos    = (int*)(ws + 7600000);      //   800,000
    int*   cnt     = (int*)(ws + 8400000);      //    50,000
    int*   base    = (int*)(ws + 8450000);      //    50,001
    int*   cursor  = (int*)(ws + 8500001);      //    50,000
    int*   bsum    = (int*)(ws + 8550001);      //       256

    k_init<<<SCAN_BLOCKS, 256, 0, stream>>>(cnt, cursor);
    k_hist<<<(N_EDGES + 255) / 256, 256, 0, stream>>>(ei, cnt);
    k_scan_blk<<<SCAN_BLOCKS, 256, 0, stream>>>(cnt, base, bsum);
    k_scan_add<<<SCAN_BLOCKS, 256, 0, stream>>>(base, bsum);
    k_scatter_idx<<<(N_EDGES + 255) / 256, 256, 0, stream>>>(ei, base, cursor, epos, ecol);
    k_node_pre<<<(N_NODES + 31) / 32, 128, 0, stream>>>(
        x, value_w, value_b, align_w, align_b, Vxb, a_dst, a_src);
    k_edge_scores<<<12500, 256, 0, stream>>>(
        ea, ei, align_w, a_dst, a_src, epos, sscores);
    k_node_fused<<<(N_NODES + 15) / 16, 256, 0, stream>>>(
        ecol, base, sscores, Vxb, x, proj_w, proj_b, ln_g, ln_b, out);
}

// Round 5
// 290.520 us; speedup vs baseline: 6.0586x; 1.0701x over previous
//
#include <hip/hip_runtime.h>
#include <hip/hip_bf16.h>
#include <math.h>

#define N_NODES 50000
#define N_EDGES 800000
#define DIM 128
#define EDIM 64
#define NH 4
#define SCAN_BLOCKS ((N_NODES + 255) / 256)   // 196

__global__ __launch_bounds__(256) void k_init(int* cnt, int* cursor) {
    int i = blockIdx.x * 256 + threadIdx.x;
    if (i < N_NODES) { cnt[i] = 0; cursor[i] = 0; }
}

__global__ __launch_bounds__(256) void k_hist(const int* __restrict__ ei, int* cnt) {
    int e = blockIdx.x * 256 + threadIdx.x;
    if (e < N_EDGES) atomicAdd(&cnt[ei[e]], 1);
}

// per-block exclusive scan (256 elems); block totals to bsum
__global__ __launch_bounds__(256) void k_scan_blk(
    const int* __restrict__ cnt, int* __restrict__ base, int* __restrict__ bsum) {
    __shared__ int wtot[4];
    int t = threadIdx.x, lane = t & 63, w = t >> 6;
    int i = blockIdx.x * 256 + t;
    int v = (i < N_NODES) ? cnt[i] : 0;
    int s = v;
    #pragma unroll
    for (int off = 1; off < 64; off <<= 1) {
        int u = __shfl_up(s, off);
        if (lane >= off) s += u;
    }
    if (lane == 63) wtot[w] = s;
    __syncthreads();
    int prefix = 0;
    for (int k = 0; k < w; ++k) prefix += wtot[k];
    if (i < N_NODES) base[i] = prefix + s - v;
    if (t == 255) bsum[blockIdx.x] = prefix + s;
}

// add scanned block offsets; each block redundantly reduces bsum[0..b)
__global__ __launch_bounds__(256) void k_scan_add(int* __restrict__ base,
                                                 const int* __restrict__ bsum) {
    __shared__ int red[4];
    int t = threadIdx.x, lane = t & 63, w = t >> 6, b = blockIdx.x;
    int val = (t < b && t < SCAN_BLOCKS) ? bsum[t] : 0;
    #pragma unroll
    for (int off = 1; off < 64; off <<= 1) val += __shfl_xor(val, off);
    if (lane == 0) red[w] = val;
    __syncthreads();
    int boff = red[0] + red[1] + red[2] + red[3];
    int i = b * 256 + t;
    if (i < N_NODES) base[i] += boff;
    if (i == 0) base[N_NODES] = N_EDGES;
}

// 32 nodes/block, 128 threads. Vx(bf16) = x@value_w + value_b; a_src = x@aw[128:256].
// (a_dst and align_b are constant per dst node per head -> cancel in segment
//  softmax exactly; not computed at all.)
__global__ __launch_bounds__(128) void k_node_pre(
    const float* __restrict__ x, const float* __restrict__ vw, const float* __restrict__ vb,
    const float* __restrict__ aw,
    unsigned int* __restrict__ Vxb,          // bf16x2 packed, 64 words per node
    float* __restrict__ a_src) {
    __shared__ float xs[32][129];
    int t = threadIdx.x;
    int nb = blockIdx.x * 32;
    #pragma unroll
    for (int i = 0; i < 8; ++i) {
        int idx = i * 128 + t;
        int m = idx >> 5, k4 = idx & 31;
        int n = nb + m;
        float4 v = make_float4(0.f, 0.f, 0.f, 0.f);
        if (n < N_NODES) v = *(const float4*)(x + (size_t)n * DIM + k4 * 4);
        xs[m][k4*4+0] = v.x; xs[m][k4*4+1] = v.y; xs[m][k4*4+2] = v.z; xs[m][k4*4+3] = v.w;
    }
    __syncthreads();
    int c = t & 31, mg = t >> 5;
    int d0 = c * 4, m0 = mg * 8;
    float acc[8][4];
    #pragma unroll
    for (int j = 0; j < 8; ++j) { acc[j][0]=0.f; acc[j][1]=0.f; acc[j][2]=0.f; acc[j][3]=0.f; }
    for (int k = 0; k < DIM; ++k) {
        float4 w = *(const float4*)(vw + (size_t)k * DIM + d0);
        #pragma unroll
        for (int j = 0; j < 8; ++j) {
            float xv = xs[m0 + j][k];
            acc[j][0] += xv * w.x; acc[j][1] += xv * w.y;
            acc[j][2] += xv * w.z; acc[j][3] += xv * w.w;
        }
    }
    float4 vb4 = *(const float4*)(vb + d0);
    #pragma unroll
    for (int j = 0; j < 8; ++j) {
        int n = nb + m0 + j;
        if (n < N_NODES) {
            __hip_bfloat162 p0 = __float22bfloat162_rn(
                make_float2(acc[j][0]+vb4.x, acc[j][1]+vb4.y));
            __hip_bfloat162 p1 = __float22bfloat162_rn(
                make_float2(acc[j][2]+vb4.z, acc[j][3]+vb4.w));
            uint2 u;
            u.x = *reinterpret_cast<unsigned int*>(&p0);
            u.y = *reinterpret_cast<unsigned int*>(&p1);
            *(uint2*)(Vxb + (size_t)n * 64 + c * 2) = u;
        }
    }
    // a_src: 32 nodes x 4 heads, 1 per thread
    {
        int m = t >> 2, h = t & 3;
        float s = 0.f;
        for (int k = 0; k < DIM; ++k) s += xs[m][k] * aw[(size_t)(DIM + k) * NH + h];
        int n = nb + m;
        if (n < N_NODES) a_src[(size_t)n * NH + h] = s;
    }
}

// PURE STREAMING: 16 lanes/edge as (quarter q, head h); weights in registers;
// reduce = 2 shuffles; coalesced write of sedge[e][h]. No indices, no scatter.
__global__ __launch_bounds__(256) void k_edge_scores(
    const float* __restrict__ ea, const float* __restrict__ aw,
    float* __restrict__ sedge) {
    int t = threadIdx.x;
    int l = t & 15, g = t >> 4;
    int h = l & 3, q = l >> 2;
    float wreg[16];
    #pragma unroll
    for (int m = 0; m < 16; ++m)
        wreg[m] = aw[1024 + (q * 16 + m) * 4 + h];
    for (int e = blockIdx.x * 16 + g; e < N_EDGES; e += gridDim.x * 16) {
        const float4* eap = (const float4*)(ea + (size_t)e * EDIM + q * 16);
        float p = 0.f;
        #pragma unroll
        for (int j = 0; j < 4; ++j) {
            float4 v = eap[j];
            p += v.x * wreg[j*4+0] + v.y * wreg[j*4+1]
               + v.z * wreg[j*4+2] + v.w * wreg[j*4+3];
        }
        p += __shfl_xor(p, 4);
        p += __shfl_xor(p, 8);
        if (q == 0) sedge[(size_t)e * 4 + h] = p;
    }
}

// 1 thread/edge: CSR slot via int atomic; moves sedge into CSR order and
// records src col. All the scatter cost lives here, off the hot paths.
__global__ __launch_bounds__(256) void k_scatter_idx(
    const int* __restrict__ ei, const int* __restrict__ base, int* cursor,
    const float* __restrict__ sedge, float* __restrict__ sscores,
    int* __restrict__ ecol) {
    int e = blockIdx.x * 256 + threadIdx.x;
    if (e < N_EDGES) {
        int row = ei[e];
        int pos = base[row] + atomicAdd(&cursor[row], 1);
        ecol[pos] = ei[N_EDGES + e];
        float4 s = *(const float4*)(sedge + (size_t)e * 4);
        *(float4*)(sscores + (size_t)pos * 4) = s;
    }
}

// 1 wave = 1 node, 4 waves/block, no LDS -> full occupancy. Pass A: online
// softmax over CSR scores (+a_src term, L2-hot). Pass B: x4-unrolled bf16 Vx
// gather. Coalesced fp32 context write.
__global__ __launch_bounds__(256) void k_aggregate(
    const int* __restrict__ base, const int* __restrict__ ecol,
    const float* __restrict__ sscores, const float* __restrict__ a_src,
    const unsigned int* __restrict__ Vxb, float* __restrict__ context) {
    int t = threadIdx.x;
    int lane = t & 63, w = t >> 6;
    int n = blockIdx.x * 4 + w;
    if (n >= N_NODES) return;
    int h = lane & 3, g = lane >> 2, hh = lane >> 4;
    int s0 = base[n], s1 = base[n + 1];
    // pass A: lane (g,h) covers slots s0+g, s0+g+16, ... (coalesced)
    float mx = -1e30f, sum = 0.f;
    for (int i = s0 + g; i < s1; i += 16) {
        int col = ecol[i];
        float s = sscores[(size_t)i * 4 + h] + a_src[(size_t)col * NH + h];
        float mn = fmaxf(mx, s);
        sum = sum * __expf(mx - mn) + __expf(s - mn);
        mx = mn;
    }
    #pragma unroll
    for (int off = 4; off < 64; off <<= 1) {
        float mo = __shfl_xor(mx, off);
        float so = __shfl_xor(sum, off);
        float mn = fmaxf(mx, mo);
        sum = sum * __expf(mx - mn) + so * __expf(mo - mn);
        mx = mn;
    }
    float mh = __shfl(mx, hh);
    float invh = __shfl(1.0f / (sum + 1e-8f), hh);
    // pass B: lane owns packed dims (2*lane, 2*lane+1), head hh; 4 edges in flight
    float acc0 = 0.f, acc1 = 0.f;
    int i = s0;
    for (; i + 3 < s1; i += 4) {
        int c0 = ecol[i], c1 = ecol[i+1], c2 = ecol[i+2], c3 = ecol[i+3];
        float t0 = sscores[(size_t)i * 4 + hh]     + a_src[(size_t)c0 * NH + hh];
        float t1 = sscores[(size_t)(i+1) * 4 + hh] + a_src[(size_t)c1 * NH + hh];
        float t2 = sscores[(size_t)(i+2) * 4 + hh] + a_src[(size_t)c2 * NH + hh];
        float t3 = sscores[(size_t)(i+3) * 4 + hh] + a_src[(size_t)c3 * NH + hh];
        unsigned int u0 = Vxb[(size_t)c0 * 64 + lane];
        unsigned int u1 = Vxb[(size_t)c1 * 64 + lane];
        unsigned int u2 = Vxb[(size_t)c2 * 64 + lane];
        unsigned int u3 = Vxb[(size_t)c3 * 64 + lane];
        float a0 = __expf(t0 - mh) * invh;
        float a1 = __expf(t1 - mh) * invh;
        float a2 = __expf(t2 - mh) * invh;
        float a3 = __expf(t3 - mh) * invh;
        float2 v0 = __bfloat1622float2(*reinterpret_cast<__hip_bfloat162*>(&u0));
        float2 v1 = __bfloat1622float2(*reinterpret_cast<__hip_bfloat162*>(&u1));
        float2 v2 = __bfloat1622float2(*reinterpret_cast<__hip_bfloat162*>(&u2));
        float2 v3 = __bfloat1622float2(*reinterpret_cast<__hip_bfloat162*>(&u3));
        acc0 += v0.x*a0; acc1 += v0.y*a0;
        acc0 += v1.x*a1; acc1 += v1.y*a1;
        acc0 += v2.x*a2; acc1 += v2.y*a2;
        acc0 += v3.x*a3; acc1 += v3.y*a3;
    }
    for (; i < s1; ++i) {
        int c = ecol[i];
        float sc = sscores[(size_t)i * 4 + hh] + a_src[(size_t)c * NH + hh];
        float a = __expf(sc - mh) * invh;
        unsigned int u = Vxb[(size_t)c * 64 + lane];
        float2 v = __bfloat1622float2(*reinterpret_cast<__hip_bfloat162*>(&u));
        acc0 += v.x * a; acc1 += v.y * a;
    }
    *(float2*)(context + (size_t)n * DIM + lane * 2) = make_float2(acc0, acc1);
}

// y = x + context@proj_w + proj_b; layernorm over D, shuffle reduce.
__global__ __launch_bounds__(128) void k_proj_ln(
    const float* __restrict__ x, const float* __restrict__ context,
    const float* __restrict__ pw, const float* __restrict__ pb,
    const float* __restrict__ lg, const float* __restrict__ lb,
    float* __restrict__ out) {
    __shared__ float cs[32][129];
    int t = threadIdx.x;
    int nb = blockIdx.x * 32;
    #pragma unroll
    for (int i = 0; i < 8; ++i) {
        int idx = i * 128 + t;
        int m = idx >> 5, k4 = idx & 31;
        int n = nb + m;
        float4 v = make_float4(0.f, 0.f, 0.f, 0.f);
        if (n < N_NODES) v = *(const float4*)(context + (size_t)n * DIM + k4 * 4);
        cs[m][k4*4+0] = v.x; cs[m][k4*4+1] = v.y; cs[m][k4*4+2] = v.z; cs[m][k4*4+3] = v.w;
    }
    __syncthreads();
    int c = t & 31, mg = t >> 5;
    int d0 = c * 4, m0 = mg * 8;
    float acc[8][4];
    #pragma unroll
    for (int j = 0; j < 8; ++j) { acc[j][0]=0.f; acc[j][1]=0.f; acc[j][2]=0.f; acc[j][3]=0.f; }
    for (int k = 0; k < DIM; ++k) {
        float4 w = *(const float4*)(pw + (size_t)k * DIM + d0);
        #pragma unroll
        for (int j = 0; j < 8; ++j) {
            float cv = cs[m0 + j][k];
            acc[j][0] += cv * w.x; acc[j][1] += cv * w.y;
            acc[j][2] += cv * w.z; acc[j][3] += cv * w.w;
        }
    }
    float4 pb4 = *(const float4*)(pb + d0);
    float4 g4  = *(const float4*)(lg + d0);
    float4 b4  = *(const float4*)(lb + d0);
    #pragma unroll
    for (int j = 0; j < 8; ++j) {
        int n = nb + m0 + j;
        float4 xv = make_float4(0.f, 0.f, 0.f, 0.f);
        if (n < N_NODES) xv = *(const float4*)(x + (size_t)n * DIM + d0);
        float y0 = xv.x + acc[j][0] + pb4.x;
        float y1 = xv.y + acc[j][1] + pb4.y;
        float y2 = xv.z + acc[j][2] + pb4.z;
        float y3 = xv.w + acc[j][3] + pb4.w;
        float ps = y0 + y1 + y2 + y3;
        float pq = y0*y0 + y1*y1 + y2*y2 + y3*y3;
        #pragma unroll
        for (int off = 1; off < 32; off <<= 1) {
            ps += __shfl_xor(ps, off);
            pq += __shfl_xor(pq, off);
        }
        float mu = ps * (1.0f / DIM);
        float var = pq * (1.0f / DIM) - mu * mu;
        float rstd = rsqrtf(var + 1e-5f);
        if (n < N_NODES) {
            float4 o;
            o.x = (y0 - mu) * rstd * g4.x + b4.x;
            o.y = (y1 - mu) * rstd * g4.y + b4.y;
            o.z = (y2 - mu) * rstd * g4.z + b4.z;
            o.w = (y3 - mu) * rstd * g4.w + b4.w;
            *(float4*)(out + (size_t)n * DIM + d0) = o;
        }
    }
}

extern "C" void kernel_launch(void* const* d_in, const int* in_sizes, int n_in,
                              void* d_out, int out_size, void* d_ws, size_t ws_size,
                              hipStream_t stream) {
    const float* x       = (const float*)d_in[0];
    const int*   ei      = (const int*)  d_in[1];
    const float* ea      = (const float*)d_in[2];
    const float* align_w = (const float*)d_in[3];
    const float* value_w = (const float*)d_in[5];
    const float* value_b = (const float*)d_in[6];
    const float* proj_w  = (const float*)d_in[7];
    const float* proj_b  = (const float*)d_in[8];
    const float* ln_g    = (const float*)d_in[9];
    const float* ln_b    = (const float*)d_in[10];
    float* out = (float*)d_out;
    float* ws  = (float*)d_ws;

    // workspace (float slots): ~17.15M floats = 68.6 MB
    unsigned int* Vxb = (unsigned int*)ws;      // 3,200,000 words (bf16 Vx)
    float* a_src   = ws + 3200000;              //   200,000
    float* sedge   = ws + 3400000;              // 3,200,000 (edge-ordered [e][4])
    float* sscores = ws + 6600000;              // 3,200,000 (CSR-ordered [pos][4])
    float* context = ws + 9800000;              // 6,400,000
    int*   ecol    = (int*)(ws + 16200000);     //   800,000
    int*   cnt     = (int*)(ws + 17000000);     //    50,000
    int*   base    = (int*)(ws + 17050000);     //    50,001
    int*   cursor  = (int*)(ws + 17100001);     //    50,000
    int*   bsum    = (int*)(ws + 17150001);     //       256

    k_init<<<SCAN_BLOCKS, 256, 0, stream>>>(cnt, cursor);
    k_hist<<<(N_EDGES + 255) / 256, 256, 0, stream>>>(ei, cnt);
    k_scan_blk<<<SCAN_BLOCKS, 256, 0, stream>>>(cnt, base, bsum);
    k_scan_add<<<SCAN_BLOCKS, 256, 0, stream>>>(base, bsum);
    k_node_pre<<<(N_NODES + 31) / 32, 128, 0, stream>>>(
        x, value_w, value_b, align_w, Vxb, a_src);
    k_edge_scores<<<12500, 256, 0, stream>>>(ea, align_w, sedge);
    k_scatter_idx<<<(N_EDGES + 255) / 256, 256, 0, stream>>>(
        ei, base, cursor, sedge, sscores, ecol);
    k_aggregate<<<(N_NODES + 3) / 4, 256, 0, stream>>>(
        base, ecol, sscores, a_src, Vxb, context);
    k_proj_ln<<<(N_NODES + 31) / 32, 128, 0, stream>>>(
        x, context, proj_w, proj_b, ln_g, ln_b, out);
}

// Round 6
// 281.518 us; speedup vs baseline: 6.2523x; 1.0320x over previous
//
#include <hip/hip_runtime.h>
#include <hip/hip_bf16.h>
#include <math.h>

#define N_NODES 50000
#define N_EDGES 800000
#define DIM 128
#define EDIM 64
#define NH 4
#define SCAN_BLOCKS ((N_NODES + 255) / 256)   // 196

__global__ __launch_bounds__(256) void k_init(int* cnt, int* cursor) {
    int i = blockIdx.x * 256 + threadIdx.x;
    if (i < N_NODES) { cnt[i] = 0; cursor[i] = 0; }
}

__global__ __launch_bounds__(256) void k_hist(const int* __restrict__ ei, int* cnt) {
    int e = blockIdx.x * 256 + threadIdx.x;
    if (e < N_EDGES) atomicAdd(&cnt[ei[e]], 1);
}

// per-block exclusive scan (256 elems); block totals to bsum
__global__ __launch_bounds__(256) void k_scan_blk(
    const int* __restrict__ cnt, int* __restrict__ base, int* __restrict__ bsum) {
    __shared__ int wtot[4];
    int t = threadIdx.x, lane = t & 63, w = t >> 6;
    int i = blockIdx.x * 256 + t;
    int v = (i < N_NODES) ? cnt[i] : 0;
    int s = v;
    #pragma unroll
    for (int off = 1; off < 64; off <<= 1) {
        int u = __shfl_up(s, off);
        if (lane >= off) s += u;
    }
    if (lane == 63) wtot[w] = s;
    __syncthreads();
    int prefix = 0;
    for (int k = 0; k < w; ++k) prefix += wtot[k];
    if (i < N_NODES) base[i] = prefix + s - v;
    if (t == 255) bsum[blockIdx.x] = prefix + s;
}

// add scanned block offsets; each block redundantly reduces bsum[0..b)
__global__ __launch_bounds__(256) void k_scan_add(int* __restrict__ base,
                                                 const int* __restrict__ bsum) {
    __shared__ int red[4];
    int t = threadIdx.x, lane = t & 63, w = t >> 6, b = blockIdx.x;
    int val = (t < b && t < SCAN_BLOCKS) ? bsum[t] : 0;
    #pragma unroll
    for (int off = 1; off < 64; off <<= 1) val += __shfl_xor(val, off);
    if (lane == 0) red[w] = val;
    __syncthreads();
    int boff = red[0] + red[1] + red[2] + red[3];
    int i = b * 256 + t;
    if (i < N_NODES) base[i] += boff;
    if (i == 0) base[N_NODES] = N_EDGES;
}

// 1 thread/edge: CSR slot via int atomic; builds epos (edge->slot) and ecol.
__global__ __launch_bounds__(256) void k_scatter_idx(
    const int* __restrict__ ei, const int* __restrict__ base, int* cursor,
    int* __restrict__ epos, int* __restrict__ ecol) {
    int e = blockIdx.x * 256 + threadIdx.x;
    if (e < N_EDGES) {
        int row = ei[e];
        int pos = base[row] + atomicAdd(&cursor[row], 1);
        epos[e] = pos;
        ecol[pos] = ei[N_EDGES + e];
    }
}

// 32 nodes/block, 128 threads. Vx(bf16) = x@value_w + value_b; a_src = x@aw[128:256].
// (a_dst and align_b cancel in segment softmax; never computed.)
__global__ __launch_bounds__(128) void k_node_pre(
    const float* __restrict__ x, const float* __restrict__ vw, const float* __restrict__ vb,
    const float* __restrict__ aw,
    unsigned int* __restrict__ Vxb,          // bf16x2 packed, 64 words per node
    float* __restrict__ a_src) {
    __shared__ float xs[32][129];
    int t = threadIdx.x;
    int nb = blockIdx.x * 32;
    #pragma unroll
    for (int i = 0; i < 8; ++i) {
        int idx = i * 128 + t;
        int m = idx >> 5, k4 = idx & 31;
        int n = nb + m;
        float4 v = make_float4(0.f, 0.f, 0.f, 0.f);
        if (n < N_NODES) v = *(const float4*)(x + (size_t)n * DIM + k4 * 4);
        xs[m][k4*4+0] = v.x; xs[m][k4*4+1] = v.y; xs[m][k4*4+2] = v.z; xs[m][k4*4+3] = v.w;
    }
    __syncthreads();
    int c = t & 31, mg = t >> 5;
    int d0 = c * 4, m0 = mg * 8;
    float acc[8][4];
    #pragma unroll
    for (int j = 0; j < 8; ++j) { acc[j][0]=0.f; acc[j][1]=0.f; acc[j][2]=0.f; acc[j][3]=0.f; }
    for (int k = 0; k < DIM; ++k) {
        float4 w = *(const float4*)(vw + (size_t)k * DIM + d0);
        #pragma unroll
        for (int j = 0; j < 8; ++j) {
            float xv = xs[m0 + j][k];
            acc[j][0] += xv * w.x; acc[j][1] += xv * w.y;
            acc[j][2] += xv * w.z; acc[j][3] += xv * w.w;
        }
    }
    float4 vb4 = *(const float4*)(vb + d0);
    #pragma unroll
    for (int j = 0; j < 8; ++j) {
        int n = nb + m0 + j;
        if (n < N_NODES) {
            __hip_bfloat162 p0 = __float22bfloat162_rn(
                make_float2(acc[j][0]+vb4.x, acc[j][1]+vb4.y));
            __hip_bfloat162 p1 = __float22bfloat162_rn(
                make_float2(acc[j][2]+vb4.z, acc[j][3]+vb4.w));
            uint2 u;
            u.x = *reinterpret_cast<unsigned int*>(&p0);
            u.y = *reinterpret_cast<unsigned int*>(&p1);
            *(uint2*)(Vxb + (size_t)n * 64 + c * 2) = u;
        }
    }
    // a_src: 32 nodes x 4 heads, 1 per thread
    {
        int m = t >> 2, h = t & 3;
        float s = 0.f;
        for (int k = 0; k < DIM; ++k) s += xs[m][k] * aw[(size_t)(DIM + k) * NH + h];
        int n = nb + m;
        if (n < N_NODES) a_src[(size_t)n * NH + h] = s;
    }
}

// 16 lanes/edge as (quarter q, head h): weights in registers; reduce = 2
// shuffles; q==0 lanes add a_src[col] and scatter straight into CSR slot
// epos[e]. No atomics, no intermediate sedge buffer.
__global__ __launch_bounds__(256) void k_edge_scores(
    const float* __restrict__ ea, const int* __restrict__ ei,
    const float* __restrict__ aw, const float* __restrict__ a_src,
    const int* __restrict__ epos, float* __restrict__ sscores) {
    int t = threadIdx.x;
    int l = t & 15, g = t >> 4;
    int h = l & 3, q = l >> 2;
    float wreg[16];
    #pragma unroll
    for (int m = 0; m < 16; ++m)
        wreg[m] = aw[1024 + (q * 16 + m) * 4 + h];
    for (int e = blockIdx.x * 16 + g; e < N_EDGES; e += gridDim.x * 16) {
        const float4* eap = (const float4*)(ea + (size_t)e * EDIM + q * 16);
        float p = 0.f;
        #pragma unroll
        for (int j = 0; j < 4; ++j) {
            float4 v = eap[j];
            p += v.x * wreg[j*4+0] + v.y * wreg[j*4+1]
               + v.z * wreg[j*4+2] + v.w * wreg[j*4+3];
        }
        p += __shfl_xor(p, 4);
        p += __shfl_xor(p, 8);
        if (q == 0) {
            int col = ei[N_EDGES + e];
            int pos = epos[e];
            sscores[(size_t)pos * 4 + h] = p + a_src[(size_t)col * NH + h];
        }
    }
}

// 1 wave = 1 node, 4 waves/block, no LDS. Pass A: online softmax over CSR
// scores (a_src already folded in). Pass B: 16 lanes/edge x 4 edge-groups —
// each lane loads uint4 (8 bf16 dims); one dwordx4 instr gathers 4 edges
// (1 KB in flight per instr); cross-group reduce = 2 shuffles per acc.
__global__ __launch_bounds__(256) void k_aggregate(
    const int* __restrict__ base, const int* __restrict__ ecol,
    const float* __restrict__ sscores,
    const unsigned int* __restrict__ Vxb, float* __restrict__ context) {
    int t = threadIdx.x;
    int lane = t & 63, w = t >> 6;
    int n = blockIdx.x * 4 + w;
    if (n >= N_NODES) return;
    int s0 = base[n], s1 = base[n + 1];
    // ---- pass A: lane (g4,h) covers slots s0+g4, +16, ... (coalesced 256B/iter)
    int h = lane & 3, g4 = lane >> 2;
    float mx = -1e30f, sum = 0.f;
    for (int i = s0 + g4; i < s1; i += 16) {
        float s = sscores[(size_t)i * 4 + h];
        float mn = fmaxf(mx, s);
        sum = sum * __expf(mx - mn) + __expf(s - mn);
        mx = mn;
    }
    #pragma unroll
    for (int off = 4; off < 64; off <<= 1) {
        float mo = __shfl_xor(mx, off);
        float so = __shfl_xor(sum, off);
        float mn = fmaxf(mx, mo);
        sum = sum * __expf(mx - mn) + so * __expf(mo - mn);
        mx = mn;
    }
    // lane now holds full-segment (mx,sum) for head h = lane&3
    // ---- pass B: group grp = lane>>4 owns edges s0+grp, +4, +8, ...
    //      lane l = lane&15 owns dims 8l..8l+7 (head hd = l>>2)
    int l = lane & 15, grp = lane >> 4;
    int hd = l >> 2;
    float mh  = __shfl(mx, hd);
    float inv = __shfl(1.0f / (sum + 1e-8f), hd);
    float a0=0.f,a1=0.f,a2=0.f,a3=0.f,a4=0.f,a5=0.f,a6=0.f,a7=0.f;
    #pragma unroll 2
    for (int ip = s0 + grp; ip < s1; ip += 4) {
        int c = ecol[ip];
        float sc = sscores[(size_t)ip * 4 + hd];
        uint4 u = *(const uint4*)(Vxb + (size_t)c * 64 + l * 4);
        float al = __expf(sc - mh) * inv;
        float f0 = __uint_as_float(u.x << 16), f1 = __uint_as_float(u.x & 0xffff0000u);
        float f2 = __uint_as_float(u.y << 16), f3 = __uint_as_float(u.y & 0xffff0000u);
        float f4 = __uint_as_float(u.z << 16), f5 = __uint_as_float(u.z & 0xffff0000u);
        float f6 = __uint_as_float(u.w << 16), f7 = __uint_as_float(u.w & 0xffff0000u);
        a0 += f0*al; a1 += f1*al; a2 += f2*al; a3 += f3*al;
        a4 += f4*al; a5 += f5*al; a6 += f6*al; a7 += f7*al;
    }
    // reduce the 4 edge-groups (lanes l, l+16, l+32, l+48)
    #pragma unroll
    for (int off = 16; off < 64; off <<= 1) {
        a0 += __shfl_xor(a0, off); a1 += __shfl_xor(a1, off);
        a2 += __shfl_xor(a2, off); a3 += __shfl_xor(a3, off);
        a4 += __shfl_xor(a4, off); a5 += __shfl_xor(a5, off);
        a6 += __shfl_xor(a6, off); a7 += __shfl_xor(a7, off);
    }
    if (lane < 16) {
        float* cp = context + (size_t)n * DIM + l * 8;
        *(float4*)(cp)     = make_float4(a0, a1, a2, a3);
        *(float4*)(cp + 4) = make_float4(a4, a5, a6, a7);
    }
}

// y = x + context@proj_w + proj_b; layernorm over D, shuffle reduce.
__global__ __launch_bounds__(128) void k_proj_ln(
    const float* __restrict__ x, const float* __restrict__ context,
    const float* __restrict__ pw, const float* __restrict__ pb,
    const float* __restrict__ lg, const float* __restrict__ lb,
    float* __restrict__ out) {
    __shared__ float cs[32][129];
    int t = threadIdx.x;
    int nb = blockIdx.x * 32;
    #pragma unroll
    for (int i = 0; i < 8; ++i) {
        int idx = i * 128 + t;
        int m = idx >> 5, k4 = idx & 31;
        int n = nb + m;
        float4 v = make_float4(0.f, 0.f, 0.f, 0.f);
        if (n < N_NODES) v = *(const float4*)(context + (size_t)n * DIM + k4 * 4);
        cs[m][k4*4+0] = v.x; cs[m][k4*4+1] = v.y; cs[m][k4*4+2] = v.z; cs[m][k4*4+3] = v.w;
    }
    __syncthreads();
    int c = t & 31, mg = t >> 5;
    int d0 = c * 4, m0 = mg * 8;
    float acc[8][4];
    #pragma unroll
    for (int j = 0; j < 8; ++j) { acc[j][0]=0.f; acc[j][1]=0.f; acc[j][2]=0.f; acc[j][3]=0.f; }
    for (int k = 0; k < DIM; ++k) {
        float4 w = *(const float4*)(pw + (size_t)k * DIM + d0);
        #pragma unroll
        for (int j = 0; j < 8; ++j) {
            float cv = cs[m0 + j][k];
            acc[j][0] += cv * w.x; acc[j][1] += cv * w.y;
            acc[j][2] += cv * w.z; acc[j][3] += cv * w.w;
        }
    }
    float4 pb4 = *(const float4*)(pb + d0);
    float4 g4  = *(const float4*)(lg + d0);
    float4 b4  = *(const float4*)(lb + d0);
    #pragma unroll
    for (int j = 0; j < 8; ++j) {
        int n = nb + m0 + j;
        float4 xv = make_float4(0.f, 0.f, 0.f, 0.f);
        if (n < N_NODES) xv = *(const float4*)(x + (size_t)n * DIM + d0);
        float y0 = xv.x + acc[j][0] + pb4.x;
        float y1 = xv.y + acc[j][1] + pb4.y;
        float y2 = xv.z + acc[j][2] + pb4.z;
        float y3 = xv.w + acc[j][3] + pb4.w;
        float ps = y0 + y1 + y2 + y3;
        float pq = y0*y0 + y1*y1 + y2*y2 + y3*y3;
        #pragma unroll
        for (int off = 1; off < 32; off <<= 1) {
            ps += __shfl_xor(ps, off);
            pq += __shfl_xor(pq, off);
        }
        float mu = ps * (1.0f / DIM);
        float var = pq * (1.0f / DIM) - mu * mu;
        float rstd = rsqrtf(var + 1e-5f);
        if (n < N_NODES) {
            float4 o;
            o.x = (y0 - mu) * rstd * g4.x + b4.x;
            o.y = (y1 - mu) * rstd * g4.y + b4.y;
            o.z = (y2 - mu) * rstd * g4.z + b4.z;
            o.w = (y3 - mu) * rstd * g4.w + b4.w;
            *(float4*)(out + (size_t)n * DIM + d0) = o;
        }
    }
}

extern "C" void kernel_launch(void* const* d_in, const int* in_sizes, int n_in,
                              void* d_out, int out_size, void* d_ws, size_t ws_size,
                              hipStream_t stream) {
    const float* x       = (const float*)d_in[0];
    const int*   ei      = (const int*)  d_in[1];
    const float* ea      = (const float*)d_in[2];
    const float* align_w = (const float*)d_in[3];
    const float* value_w = (const float*)d_in[5];
    const float* value_b = (const float*)d_in[6];
    const float* proj_w  = (const float*)d_in[7];
    const float* proj_b  = (const float*)d_in[8];
    const float* ln_g    = (const float*)d_in[9];
    const float* ln_b    = (const float*)d_in[10];
    float* out = (float*)d_out;
    float* ws  = (float*)d_ws;

    // workspace (float slots): ~14.75M floats = 59 MB
    unsigned int* Vxb = (unsigned int*)ws;      // 3,200,000 words (bf16 Vx)
    float* a_src   = ws + 3200000;              //   200,000
    float* sscores = ws + 3400000;              // 3,200,000 (CSR-ordered [pos][4], a_src folded)
    float* context = ws + 6600000;              // 6,400,000
    int*   ecol    = (int*)(ws + 13000000);     //   800,000
    int*   epos    = (int*)(ws + 13800000);     //   800,000
    int*   cnt     = (int*)(ws + 14600000);     //    50,000
    int*   base    = (int*)(ws + 14650000);     //    50,001
    int*   cursor  = (int*)(ws + 14700001);     //    50,000
    int*   bsum    = (int*)(ws + 14750001);     //       256

    k_init<<<SCAN_BLOCKS, 256, 0, stream>>>(cnt, cursor);
    k_hist<<<(N_EDGES + 255) / 256, 256, 0, stream>>>(ei, cnt);
    k_scan_blk<<<SCAN_BLOCKS, 256, 0, stream>>>(cnt, base, bsum);
    k_scan_add<<<SCAN_BLOCKS, 256, 0, stream>>>(base, bsum);
    k_scatter_idx<<<(N_EDGES + 255) / 256, 256, 0, stream>>>(ei, base, cursor, epos, ecol);
    k_node_pre<<<(N_NODES + 31) / 32, 128, 0, stream>>>(
        x, value_w, value_b, align_w, Vxb, a_src);
    k_edge_scores<<<12500, 256, 0, stream>>>(ea, ei, align_w, a_src, epos, sscores);
    k_aggregate<<<(N_NODES + 3) / 4, 256, 0, stream>>>(
        base, ecol, sscores, Vxb, context);
    k_proj_ln<<<(N_NODES + 31) / 32, 128, 0, stream>>>(
        x, context, proj_w, proj_b, ln_g, ln_b, out);
}